// Round 1
// 620.048 us; speedup vs baseline: 1.0823x; 1.0823x over previous
//
#include <hip/hip_runtime.h>
#include <stdint.h>

#define K_DIM 1024
#define N_DIM 1024
#define M_MAX 65536

// GEMM geometry: 256x256 tile, BK=32, 8 waves (2M x 4N), 512 threads,
// 3-stage LDS ring buffer (96 KiB) for cross-barrier prefetch depth.
#define BM 256
#define BN 256
#define BK 32
#define NKT (K_DIM / BK)      // 32 k-tiles
#define NBUF 3
#define A_TILE (BM * BK)      // 8192 ushorts = 16 KiB
#define B_TILE (BN * BK)

typedef __attribute__((ext_vector_type(8))) __bf16 bf16x8;
typedef __attribute__((ext_vector_type(4))) float f32x4;

// Static device storage (fully rewritten every call; BSS, no load-time cost)
__device__ __align__(16) unsigned short g_wq[N_DIM * K_DIM];          // ternary W as bf16 bits
__device__ __align__(16) unsigned short g_xq[(size_t)M_MAX * K_DIM];  // x as bf16 bits (128 MB)
__device__ double g_partial[256];
__device__ float g_scale;

__device__ __forceinline__ unsigned int pack_bf16(float hi, float lo) {
  // (trunc_bf16(hi) << 16) | trunc_bf16(lo) in one v_perm_b32
  return __builtin_amdgcn_perm(__float_as_uint(hi), __float_as_uint(lo), 0x07060302u);
}

// ---- Kernel 1: partial sums of |w| (double accumulation, deterministic) ----
__global__ void absum_kernel(const float* __restrict__ w) {
  const int tid = threadIdx.x, bid = blockIdx.x;
  const float4* w4 = (const float4*)w;  // 262144 float4s total
  double s = 0.0;
#pragma unroll
  for (int i = 0; i < 4; i++) {
    float4 v = w4[bid * 1024 + i * 256 + tid];
    s += (double)fabsf(v.x) + (double)fabsf(v.y) + (double)fabsf(v.z) + (double)fabsf(v.w);
  }
#pragma unroll
  for (int o = 32; o > 0; o >>= 1) s += __shfl_down(s, o);
  __shared__ double sm[4];
  if ((tid & 63) == 0) sm[tid >> 6] = s;
  __syncthreads();
  if (tid == 0) g_partial[bid] = sm[0] + sm[1] + sm[2] + sm[3];
}

// ---- Kernel 2: final reduce -> scale = max(mean|w|, 1e-5) ----
__global__ void scale_kernel() {
  const int tid = threadIdx.x;
  double v = g_partial[tid];
#pragma unroll
  for (int o = 32; o > 0; o >>= 1) v += __shfl_down(v, o);
  __shared__ double sm[4];
  if ((tid & 63) == 0) sm[tid >> 6] = v;
  __syncthreads();
  if (tid == 0) {
    double total = sm[0] + sm[1] + sm[2] + sm[3];
    double mean = total * (1.0 / 1048576.0);  // exact pow2 divide
    g_scale = (float)fmax(mean, 1e-5);
  }
}

// ---- Kernel 3: quantize W -> ternary bf16 {-1,0,1} (exact in bf16) ----
__global__ void quant_kernel(const float* __restrict__ w) {
  const int idx = blockIdx.x * 256 + threadIdx.x;  // x4 floats
  const float s = g_scale;
  float4 v = ((const float4*)w)[idx];
  float q0 = fminf(1.f, fmaxf(-1.f, rintf(v.x / s)));
  float q1 = fminf(1.f, fmaxf(-1.f, rintf(v.y / s)));
  float q2 = fminf(1.f, fmaxf(-1.f, rintf(v.z / s)));
  float q3 = fminf(1.f, fmaxf(-1.f, rintf(v.w / s)));
  ushort4 o;
  o.x = (unsigned short)(__float_as_uint(q0) >> 16);
  o.y = (unsigned short)(__float_as_uint(q1) >> 16);
  o.z = (unsigned short)(__float_as_uint(q2) >> 16);
  o.w = (unsigned short)(__float_as_uint(q3) >> 16);
  ((ushort4*)g_wq)[idx] = o;
}

// ---- Kernel 4: convert x fp32 -> bf16 (truncation, streaming) ----
__global__ __launch_bounds__(256) void convert_x(const float* __restrict__ x) {
  const size_t t = (size_t)blockIdx.x * 256 + threadIdx.x;  // 8 floats per thread
  const float4* x4 = (const float4*)x;
  float4 a = x4[t * 2];
  float4 b = x4[t * 2 + 1];
  uint4 o;
  o.x = pack_bf16(a.y, a.x);
  o.y = pack_bf16(a.w, a.z);
  o.z = pack_bf16(b.y, b.x);
  o.w = pack_bf16(b.w, b.z);
  ((uint4*)g_xq)[t] = o;
}

// ---- Kernel 5: GEMM  C[M,N] = (Aq[M,K] @ Wq[N,K]^T) * scale ----
// 256x256 tile, BK=32, 8 waves (2x4), 3-stage ring LDS, counted vmcnt(4),
// per-tile {ds_read || global_load_lds || MFMA} interleave, setprio on MFMA,
// 16B-chunk XOR swizzle on LDS reads via pre-swizzled global source.
__global__ __launch_bounds__(512, 2) void bitlinear_gemm(float* __restrict__ C) {
  __shared__ __align__(16) unsigned short As[NBUF * A_TILE];  // 48 KiB
  __shared__ __align__(16) unsigned short Bs[NBUF * B_TILE];  // 48 KiB

  const int tid  = threadIdx.x;
  const int lane = tid & 63;
  const int wave = tid >> 6;   // 0..7
  const int wm   = wave >> 2;  // 0..1  -> 128 rows each
  const int wn   = wave & 3;   // 0..3  -> 64 cols each
  const int lm   = lane & 15;
  const int lq   = lane >> 4;

  // XCD-locality swizzle (nwg = 1024, divisible by 8 -> bijective):
  // XCD x gets logical tiles [x*128, x*128+128) -> each A-panel's 4 n-tiles
  // plus neighbors stay on one XCD's L2.
  const int b       = blockIdx.x;
  const int cpx     = (int)(gridDim.x >> 3);
  const int logical = (b & 7) * cpx + (b >> 3);
  const int mt      = logical >> 2;  // N_DIM/BN == 4 n-tiles
  const int nt      = logical & 3;
  const int m0      = mt * BM;
  const int n0      = nt * BN;

  f32x4 acc[8][4];
#pragma unroll
  for (int i = 0; i < 8; i++)
#pragma unroll
    for (int j = 0; j < 4; j++) acc[i][j] = (f32x4){0.f, 0.f, 0.f, 0.f};

  // --- Staging geometry -------------------------------------------------
  // Wave w stages rows [w*32, w*32+32) of the 256-row tile: 2 instrs of
  // 16 rows x 32 k each (64 lanes x 16B). LDS dest is LINEAR (glds rule);
  // the 16B-chunk swizzle chunk' = chunk ^ ((row>>1)&3) is realized by
  // permuting the GLOBAL source chunk: lane l fetches logical chunk
  // (l&3)^((l>>3)&3) (involution; rows per instr start at multiples of 16).
  const int cswz = ((lane & 3) ^ ((lane >> 3) & 3)) * 8;  // ushort offset
  const unsigned short* aSrc =
      g_xq + (size_t)(m0 + wave * 32 + (lane >> 2)) * K_DIM + cswz;
  const unsigned short* bSrc =
      g_wq + (size_t)(n0 + wave * 32 + (lane >> 2)) * K_DIM + cswz;
  const int ldsDst = wave * 32 * BK;  // ushort offset of this wave's rows

#define STAGE_A(tt, bb)                                                        \
  do {                                                                         \
    const unsigned short* s_ = aSrc + (tt) * BK;                               \
    unsigned short* d_ = &As[(bb) * A_TILE + ldsDst];                          \
    __builtin_amdgcn_global_load_lds(                                          \
        (const __attribute__((address_space(1))) unsigned int*)s_,             \
        (__attribute__((address_space(3))) unsigned int*)d_, 16, 0, 0);        \
    __builtin_amdgcn_global_load_lds(                                          \
        (const __attribute__((address_space(1))) unsigned int*)(s_ + 16 * K_DIM), \
        (__attribute__((address_space(3))) unsigned int*)(d_ + 16 * BK), 16, 0, 0); \
  } while (0)

#define STAGE_B(tt, bb)                                                        \
  do {                                                                         \
    const unsigned short* s_ = bSrc + (tt) * BK;                               \
    unsigned short* d_ = &Bs[(bb) * B_TILE + ldsDst];                          \
    __builtin_amdgcn_global_load_lds(                                          \
        (const __attribute__((address_space(1))) unsigned int*)s_,             \
        (__attribute__((address_space(3))) unsigned int*)d_, 16, 0, 0);        \
    __builtin_amdgcn_global_load_lds(                                          \
        (const __attribute__((address_space(1))) unsigned int*)(s_ + 16 * K_DIM), \
        (__attribute__((address_space(3))) unsigned int*)(d_ + 16 * BK), 16, 0, 0); \
  } while (0)

  // --- LDS read addressing (swizzled) -----------------------------------
  // Fragment row r = base + mf*16 + lm; swizzled chunk = lq ^ ((r>>1)&3).
  // Since base is a multiple of 64 and mf*16 keeps (r>>1)&3 invariant, the
  // XOR is per-thread constant. 64-lane b128 access -> uniform 8 lanes per
  // 16B bank-group (minimum aliasing; conflict-free in the m136 sense).
  const int xorc = (((lm >> 1) & 3) ^ lq) * 8;
  const int aRd  = (wm * 128 + lm) * BK + xorc;
  const int bRd  = (wn * 64 + lm) * BK + xorc;

  // --- Prologue: fill 2 of 3 ring slots ---------------------------------
  STAGE_A(0, 0);
  STAGE_B(0, 0);
  STAGE_A(1, 1);
  STAGE_B(1, 1);

  int buf = 0;
#pragma unroll 1
  for (int t = 0; t < NKT; ++t) {
    // Counted wait: own 4 loads for tile t landed (tile t+1's 4 stay in
    // flight), then barrier so every wave's staged data is visible.
    // Single asm with memory clobber = nothing crosses it either direction.
    if (t == NKT - 1)
      asm volatile("s_waitcnt vmcnt(0)\n\ts_barrier" ::: "memory");
    else
      asm volatile("s_waitcnt vmcnt(4)\n\ts_barrier" ::: "memory");

    const unsigned short* Ab = &As[buf * A_TILE + aRd];
    const unsigned short* Bb = &Bs[buf * B_TILE + bRd];
    const int nbuf = (buf + 2 >= NBUF) ? buf + 2 - NBUF : buf + 2;

    // Phase 0: read B frags + A frags (m0..3), issue A prefetch, 16 MFMA
    bf16x8 bfr[4], af[4];
#pragma unroll
    for (int nf = 0; nf < 4; ++nf) bfr[nf] = *(const bf16x8*)(Bb + nf * 16 * BK);
#pragma unroll
    for (int mf = 0; mf < 4; ++mf) af[mf] = *(const bf16x8*)(Ab + mf * 16 * BK);

    if (t + 2 < NKT) STAGE_A(t + 2, nbuf);

    __builtin_amdgcn_s_setprio(1);
#pragma unroll
    for (int mf = 0; mf < 4; ++mf)
#pragma unroll
      for (int nf = 0; nf < 4; ++nf)
        acc[mf][nf] = __builtin_amdgcn_mfma_f32_16x16x32_bf16(af[mf], bfr[nf],
                                                              acc[mf][nf], 0, 0, 0);
    __builtin_amdgcn_s_setprio(0);

    // Phase 1: read A frags (m4..7), issue B prefetch, 16 MFMA
    bf16x8 af2[4];
#pragma unroll
    for (int mf = 0; mf < 4; ++mf)
      af2[mf] = *(const bf16x8*)(Ab + (mf + 4) * 16 * BK);

    if (t + 2 < NKT) STAGE_B(t + 2, nbuf);

    __builtin_amdgcn_s_setprio(1);
#pragma unroll
    for (int mf = 0; mf < 4; ++mf)
#pragma unroll
      for (int nf = 0; nf < 4; ++nf)
        acc[mf + 4][nf] = __builtin_amdgcn_mfma_f32_16x16x32_bf16(
            af2[mf], bfr[nf], acc[mf + 4][nf], 0, 0, 0);
    __builtin_amdgcn_s_setprio(0);

    buf = (buf + 1 == NBUF) ? 0 : buf + 1;
  }
#undef STAGE_A
#undef STAGE_B

  // Epilogue: C/D layout col=lane&15, row=(lane>>4)*4+r; apply scale here
  const float s    = g_scale;
  const int   crow = m0 + wm * 128 + lq * 4;
  const int   ccol = n0 + wn * 64 + lm;
#pragma unroll
  for (int mf = 0; mf < 8; ++mf) {
#pragma unroll
    for (int nf = 0; nf < 4; ++nf) {
#pragma unroll
      for (int r = 0; r < 4; ++r) {
        C[(size_t)(crow + mf * 16 + r) * N_DIM + (ccol + nf * 16)] =
            acc[mf][nf][r] * s;
      }
    }
  }
}

extern "C" void kernel_launch(void* const* d_in, const int* in_sizes, int n_in,
                              void* d_out, int out_size, void* d_ws, size_t ws_size,
                              hipStream_t stream) {
  const float* x = (const float*)d_in[0];   // [M, 1024] fp32
  const float* w = (const float*)d_in[1];   // [1024, 1024] fp32
  float* out = (float*)d_out;               // [M, 1024] fp32
  const int M = in_sizes[0] / K_DIM;        // 65536

  hipLaunchKernelGGL(absum_kernel, dim3(256), dim3(256), 0, stream, w);
  hipLaunchKernelGGL(scale_kernel, dim3(1), dim3(256), 0, stream);
  hipLaunchKernelGGL(quant_kernel, dim3(1024), dim3(256), 0, stream, w);
  hipLaunchKernelGGL(convert_x, dim3((unsigned)((size_t)M * K_DIM / 8 / 256)), dim3(256), 0,
                     stream, x);
  hipLaunchKernelGGL(bitlinear_gemm,
                     dim3((unsigned)(((size_t)M / BM) * (N_DIM / BN))),
                     dim3(512), 0, stream, out);
}